// Round 14
// baseline (313.281 us; speedup 1.0000x reference)
//
#include <hip/hip_runtime.h>
#include <hip/hip_bf16.h>

typedef __attribute__((ext_vector_type(8))) __bf16 bf16x8;
typedef __attribute__((ext_vector_type(4))) float f32x4;

#define DDIM 256
#define KCENT 1024
#define BM 32                 // rows per block (all 4 waves share this panel)

union FragU { uint4 u; bf16x8 f; };

__device__ __forceinline__ unsigned int pk2(float lo, float hi) {
    union { __hip_bfloat16 h; unsigned short u; } a, b;
    a.h = __float2bfloat16(lo);
    b.h = __float2bfloat16(hi);
    return (unsigned int)a.u | ((unsigned int)b.u << 16);
}

// ---------------------------------------------------------------------------
// Kernel 1 (unchanged, validated): centers f32 -> bf16 + exact f32 stats.
// ---------------------------------------------------------------------------
__global__ __launch_bounds__(256) void rbf_prep_c(
    const float* __restrict__ centers, const float* __restrict__ sigmas,
    __bf16* __restrict__ cbf, float2* __restrict__ c2s)
{
    const int wave = threadIdx.x >> 6, lane = threadIdx.x & 63;
    const int r = blockIdx.x * 4 + wave;

    const float4* __restrict__ src = (const float4*)(centers + (size_t)r * DDIM);
    const float4 v = src[lane];
    float s = v.x * v.x + v.y * v.y + v.z * v.z + v.w * v.w;
#pragma unroll
    for (int m = 1; m < 64; m <<= 1) s += __shfl_xor(s, m, 64);

    uint2 p;
    p.x = pk2(v.x, v.y);
    p.y = pk2(v.z, v.w);
    ((uint2*)(cbf + (size_t)r * DDIM))[lane] = p;

    if (lane == 0) {
        const float sg = sigmas[r];
        c2s[r] = make_float2(s, -0.5f / (sg * sg));
    }
}

// ---------------------------------------------------------------------------
// Kernel 2 (R14): ZERO LDS, ZERO BARRIERS — fully independent waves.
// Why: R10-R12 (~60us) were phase-locked by block barriers at 8 waves/CU;
// every intra-loop edit was neutral. R13's direct counters showed the cost is
// latency exposure, not issue work. And cbf (512 KB) is L2-RESIDENT — staging
// it through LDS was pure overhead (Common-mistake #7).
// Structure: 1024 blocks x 256 thr; each WAVE independently owns 32 rows x
// 256 cols (wave = N-quarter; the 4 waves share the block's x panel -> L2-hot).
//  A: lane converts its MFMA A-fragment elems from global f32 into 64 VGPRs
//     of bf16 once, x^2 summed in f32 on the way; row sums distributed by
//     __shfl only (no LDS). Verbatim-validated conversion (absmax 0.0, 8x).
//  B: fragments loaded DIRECTLY from L2-resident cbf — identical (row,k)
//     address formula as the validated LDS path, minus the swizzle.
//  No __syncthreads anywhere: waves drift, so B/L2 latency of some waves
//  overlaps MFMA/epilogue of others (12 waves/CU at VGPR~140, lb(256,3)).
//  Stores drain at s_endpgm. MFMA + C/D mappings verbatim (absmax 0.0, 8x).
// ---------------------------------------------------------------------------
__global__ __launch_bounds__(256, 3) void rbf_gemm(
    const float* __restrict__ x, const __bf16* __restrict__ cbf,
    const float2* __restrict__ c2s, float* __restrict__ out)
{
    const int t = threadIdx.x;
    const int lane = t & 63, wave = t >> 6;   // wave = N-quarter (256 cols)
    const int q = lane >> 4, r16 = lane & 15;
    const int mrow0 = blockIdx.x * BM;

    // ---- A fragments straight from global f32 -> bf16 registers ----
    // rows mrow0 + fm*16 + r16; k = kw*32 + q*8 .. +8
    FragU afr[2][8];
    float s0 = 0.f, s1 = 0.f;
#pragma unroll
    for (int fm = 0; fm < 2; ++fm) {
        const float* __restrict__ rowp =
            x + (size_t)(mrow0 + fm * 16 + r16) * DDIM + q * 8;
#pragma unroll
        for (int kw = 0; kw < 8; ++kw) {
            const float4 v0 = *(const float4*)(rowp + kw * 32);
            const float4 v1 = *(const float4*)(rowp + kw * 32 + 4);
            const float s = v0.x * v0.x + v0.y * v0.y + v0.z * v0.z + v0.w * v0.w
                          + v1.x * v1.x + v1.y * v1.y + v1.z * v1.z + v1.w * v1.w;
            if (fm == 0) s0 += s; else s1 += s;
            afr[fm][kw].u = make_uint4(pk2(v0.x, v0.y), pk2(v0.z, v0.w),
                                       pk2(v1.x, v1.y), pk2(v1.z, v1.w));
        }
    }
    // q-reduce: lanes ^16/^32 sum over q -> lanes with equal r16 hold the
    // full 256-elem row sum of row (fm*16 + r16).
    s0 += __shfl_xor(s0, 16, 64); s0 += __shfl_xor(s0, 32, 64);
    s1 += __shfl_xor(s1, 16, 64); s1 += __shfl_xor(s1, 32, 64);

    // epilogue row stats via shfl (C/D row = fm*16 + q*4 + rg; lane (q*4+rg)
    // has r16 == q*4+rg, so it holds that row's sum).
    float xr[2][4];
#pragma unroll
    for (int fm = 0; fm < 2; ++fm)
#pragma unroll
        for (int rg = 0; rg < 4; ++rg)
            xr[fm][rg] = __shfl(fm ? s1 : s0, q * 4 + rg, 64);

    const char* __restrict__ cg = (const char*)cbf;
    float* outbase = out + (size_t)mrow0 * KCENT;

#pragma unroll 1
    for (int nt = 0; nt < 4; ++nt) {
        const int ncol0 = wave * 256 + nt * 64;

        f32x4 acc[2][4];
#pragma unroll
        for (int fm = 0; fm < 2; ++fm)
#pragma unroll
            for (int fn = 0; fn < 4; ++fn)
                acc[fm][fn] = (f32x4){0.f, 0.f, 0.f, 0.f};

        // 8 K-windows x {4 direct-L2 B loads + 8 MFMA}
#pragma unroll
        for (int kw = 0; kw < 8; ++kw) {
            FragU b[4];
#pragma unroll
            for (int fn = 0; fn < 4; ++fn) {
                const size_t off =
                    (size_t)(ncol0 + fn * 16 + r16) * 512 + kw * 64 + q * 16;
                b[fn].u = *(const uint4*)(cg + off);
            }
#pragma unroll
            for (int fm = 0; fm < 2; ++fm)
#pragma unroll
                for (int fn = 0; fn < 4; ++fn)
                    acc[fm][fn] = __builtin_amdgcn_mfma_f32_16x16x32_bf16(
                        afr[fm][kw].f, b[fn].f, acc[fm][fn], 0, 0, 0);
        }

        // epilogue: sqdist = x2 + c2 - 2*cross; out = exp(scale*sq)
        // C/D layout (m89-verified): col = lane&15, row = (lane>>4)*4 + reg
#pragma unroll
        for (int fm = 0; fm < 2; ++fm) {
            const int il = fm * 16 + q * 4;
#pragma unroll
            for (int fn = 0; fn < 4; ++fn) {
                const int j = ncol0 + fn * 16 + r16;
                const float2 cs = c2s[j];
#pragma unroll
                for (int rg = 0; rg < 4; ++rg) {
                    const float sq = xr[fm][rg] + cs.x - 2.0f * acc[fm][fn][rg];
                    outbase[(size_t)(il + rg) * KCENT + j] = __expf(sq * cs.y);
                }
            }
        }
    }
    // stores drain at s_endpgm
}

extern "C" void kernel_launch(void* const* d_in, const int* in_sizes, int n_in,
                              void* d_out, int out_size, void* d_ws, size_t ws_size,
                              hipStream_t stream) {
    const float* x = (const float*)d_in[0];
    const float* centers = (const float*)d_in[1];
    const float* sigmas = (const float*)d_in[2];
    float* out = (float*)d_out;

    const int Brows = in_sizes[0] / DDIM;  // 32768

    // workspace layout: cbf (512 KB) | c2s (8 KB)
    char* ws = (char*)d_ws;
    __bf16* cbf = (__bf16*)ws;
    float2* c2s = (float2*)(ws + (size_t)KCENT * DDIM * 2);

    rbf_prep_c<<<dim3(KCENT / 4), dim3(256), 0, stream>>>(centers, sigmas, cbf, c2s);
    rbf_gemm<<<dim3(Brows / BM), dim3(256), 0, stream>>>(x, cbf, c2s, out);
}

// Round 15
// 266.648 us; speedup vs baseline: 1.1749x; 1.1749x over previous
//
#include <hip/hip_runtime.h>
#include <hip/hip_bf16.h>

typedef __attribute__((ext_vector_type(8))) __bf16 bf16x8;
typedef __attribute__((ext_vector_type(4))) float f32x4;

#define DDIM 256
#define KCENT 1024

union FragU { uint4 u; bf16x8 f; };

__device__ __forceinline__ unsigned int pk2(float lo, float hi) {
    union { __hip_bfloat16 h; unsigned short u; } a, b;
    a.h = __float2bfloat16(lo);
    b.h = __float2bfloat16(hi);
    return (unsigned int)a.u | ((unsigned int)b.u << 16);
}

// ---------------------------------------------------------------------------
// Kernel 1 (unchanged, validated): centers f32 -> bf16 + exact f32 stats.
// ---------------------------------------------------------------------------
__global__ __launch_bounds__(256) void rbf_prep_c(
    const float* __restrict__ centers, const float* __restrict__ sigmas,
    __bf16* __restrict__ cbf, float2* __restrict__ c2s)
{
    const int wave = threadIdx.x >> 6, lane = threadIdx.x & 63;
    const int r = blockIdx.x * 4 + wave;

    const float4* __restrict__ src = (const float4*)(centers + (size_t)r * DDIM);
    const float4 v = src[lane];
    float s = v.x * v.x + v.y * v.y + v.z * v.z + v.w * v.w;
#pragma unroll
    for (int m = 1; m < 64; m <<= 1) s += __shfl_xor(s, m, 64);

    uint2 p;
    p.x = pk2(v.x, v.y);
    p.y = pk2(v.z, v.w);
    ((uint2*)(cbf + (size_t)r * DDIM))[lane] = p;

    if (lane == 0) {
        const float sg = sigmas[r];
        c2s[r] = make_float2(s, -0.5f / (sg * sg));
    }
}

// ---------------------------------------------------------------------------
// Kernel 2 (R15 = R14 with the register budget engineered to fit):
// R13 (VGPR 76) and R14 (VGPR 84, 75 MB spill writes) proved the latency/TLP
// theory was never tested — both occupancy attempts died of register
// allocation. This version fits 4 waves/SIMD BY CONSTRUCTION:
//   fm=1: wave owns 16 rows -> afr 32 VGPR (was 64). Live set ~110 < 128,
//   so __launch_bounds__(256,4) (VGPR cap 128, 4 blocks/CU = 16 waves/CU)
//   holds without spill — 2x the TLP of every non-spilling round so far.
// Zero LDS, zero barriers: waves fully independent (the fill-kernel regime
// that sustains 6.8 TB/s at 10% occupancy). B fragments direct from
// L2-resident cbf (formula HW-validated in R14, absmax 0.0). A conversion
// verbatim-validated (9 rounds). Each wave: 16 rows x 512 cols (8 tiles);
// block = 4 waves = 64 rows; grid = 512 M-panels x 2 N-halves = 1024.
// XCD swizzle: N-half is the fastest lid bit -> the 2 blocks sharing an
// x panel run on the SAME XCD (x fetched from HBM once, ~33.5 MB).
// ---------------------------------------------------------------------------
__global__ __launch_bounds__(256, 4) void rbf_gemm(
    const float* __restrict__ x, const __bf16* __restrict__ cbf,
    const float2* __restrict__ c2s, float* __restrict__ out)
{
    const int t = threadIdx.x;
    const int lane = t & 63, wave = t >> 6;
    const int q = lane >> 4, r16 = lane & 15;

    // bijective XCD swizzle (nwg=1024, 128 lids per XCD): lid&1 = N-half.
    const int bx = blockIdx.x;
    const int lid = (bx & 7) * (gridDim.x >> 3) + (bx >> 3);
    const int nh = lid & 1;
    const int mrow0 = (lid >> 1) * 64 + wave * 16;   // this wave's 16 rows
    const int ncolbase = nh * 512;

    // ---- A fragments straight from global f32 -> bf16 registers ----
    // rows mrow0 + r16; k = kw*32 + q*8 .. +8   (validated conversion)
    FragU afr[8];
    float s0 = 0.f;
    {
        const float* __restrict__ rowp =
            x + (size_t)(mrow0 + r16) * DDIM + q * 8;
#pragma unroll
        for (int kw = 0; kw < 8; ++kw) {
            const float4 v0 = *(const float4*)(rowp + kw * 32);
            const float4 v1 = *(const float4*)(rowp + kw * 32 + 4);
            s0 += v0.x * v0.x + v0.y * v0.y + v0.z * v0.z + v0.w * v0.w
                + v1.x * v1.x + v1.y * v1.y + v1.z * v1.z + v1.w * v1.w;
            afr[kw].u = make_uint4(pk2(v0.x, v0.y), pk2(v0.z, v0.w),
                                   pk2(v1.x, v1.y), pk2(v1.z, v1.w));
        }
    }
    // q-reduce: lanes ^16/^32 sum over q -> full 256-elem row sums per r16
    s0 += __shfl_xor(s0, 16, 64);
    s0 += __shfl_xor(s0, 32, 64);

    // epilogue row stats: C/D row = q*4+rg; lane (q*4+rg) holds that row's sum
    float xr[4];
#pragma unroll
    for (int rg = 0; rg < 4; ++rg)
        xr[rg] = __shfl(s0, q * 4 + rg, 64);

    const char* __restrict__ cg = (const char*)cbf;
    float* outbase = out + (size_t)mrow0 * KCENT;

#pragma unroll 1
    for (int nt = 0; nt < 8; ++nt) {
        const int ncol0 = ncolbase + nt * 64;

        f32x4 acc[4];
#pragma unroll
        for (int fn = 0; fn < 4; ++fn)
            acc[fn] = (f32x4){0.f, 0.f, 0.f, 0.f};

        // 8 K-windows x {4 direct-L2 B loads + 4 MFMA}
#pragma unroll
        for (int kw = 0; kw < 8; ++kw) {
            FragU b[4];
#pragma unroll
            for (int fn = 0; fn < 4; ++fn) {
                const size_t off =
                    (size_t)(ncol0 + fn * 16 + r16) * 512 + kw * 64 + q * 16;
                b[fn].u = *(const uint4*)(cg + off);
            }
#pragma unroll
            for (int fn = 0; fn < 4; ++fn)
                acc[fn] = __builtin_amdgcn_mfma_f32_16x16x32_bf16(
                    afr[kw].f, b[fn].f, acc[fn], 0, 0, 0);
        }

        // epilogue: sqdist = x2 + c2 - 2*cross; out = exp(scale*sq)
        // C/D layout (m89-verified): col = lane&15, row = (lane>>4)*4 + reg
#pragma unroll
        for (int fn = 0; fn < 4; ++fn) {
            const int j = ncol0 + fn * 16 + r16;
            const float2 cs = c2s[j];
#pragma unroll
            for (int rg = 0; rg < 4; ++rg) {
                const float sq = xr[rg] + cs.x - 2.0f * acc[fn][rg];
                outbase[(size_t)(q * 4 + rg) * KCENT + j] = __expf(sq * cs.y);
            }
        }
    }
    // stores drain at s_endpgm
}

extern "C" void kernel_launch(void* const* d_in, const int* in_sizes, int n_in,
                              void* d_out, int out_size, void* d_ws, size_t ws_size,
                              hipStream_t stream) {
    const float* x = (const float*)d_in[0];
    const float* centers = (const float*)d_in[1];
    const float* sigmas = (const float*)d_in[2];
    float* out = (float*)d_out;

    const int Brows = in_sizes[0] / DDIM;  // 32768

    // workspace layout: cbf (512 KB) | c2s (8 KB)
    char* ws = (char*)d_ws;
    __bf16* cbf = (__bf16*)ws;
    float2* c2s = (float2*)(ws + (size_t)KCENT * DDIM * 2);

    rbf_prep_c<<<dim3(KCENT / 4), dim3(256), 0, stream>>>(centers, sigmas, cbf, c2s);

    const int nwg = (Brows / 64) * 2;   // 1024 blocks: 512 M-panels x 2 N-halves
    rbf_gemm<<<dim3(nwg), dim3(256), 0, stream>>>(x, cbf, c2s, out);
}